// Round 9
// baseline (713.305 us; speedup 1.0000x reference)
//
#include <hip/hip_runtime.h>

// Problem constants (match reference setup_inputs)
#define NN 50000
#define EE 800000
#define DD 256
#define LL 3
#define GG 512
#define MPAD 50048   // 1564 * 32, GEMM row-tile padding
#define NSH 8        // column shards (one per XCD); 32 cols = 64 B per shard
#define GATHER_GRID (782 * NSH)   // 782 groups of 64 nodes x 8 shards

typedef __attribute__((ext_vector_type(4))) _Float16 half4;
typedef __attribute__((ext_vector_type(8))) _Float16 half8;
typedef __attribute__((ext_vector_type(16))) float floatx16;
typedef __attribute__((ext_vector_type(4))) int int4v;

// h lives SHARD-MAJOR: [shard][MPAD][32] halfs (shard s = cols [32s,32s+32);
// 3.2 MB/shard < 4 MB XCD L2 -> L2-resident during gather; round 5 verified
// FETCH 185->26 MB). agg is ROW-major [MPAD][256] (mlp streams it).

// ---------------------------------------------------------------------------
// Fused prep kernel (independent work, split by blockIdx range):
//   [0, 12500)        : x fp32 -> fp16 convert (into shard-major h)
//   [12500, 12692)    : weight pack (192 blocks)
//   [12692, 15817)    : degree histogram (3125 blocks)
// ---------------------------------------------------------------------------
#define CONV_B 12500
#define WPK_B  192
#define HIST_B 3125

__global__ void k_prep(const float* __restrict__ x, _Float16* __restrict__ h16,
                       const float* __restrict__ Ws1, const float* __restrict__ Ws2,
                       _Float16* __restrict__ Wp,
                       const int* __restrict__ dst, int* __restrict__ deg) {
    int b = blockIdx.x;
    if (b < CONV_B) {
        int i = b * 256 + threadIdx.x;  // float4 groups, NN*64 total
        if (i >= NN * 64) return;
        float4 v = ((const float4*)x)[i];
        half4 o;
        o.x = (_Float16)v.x; o.y = (_Float16)v.y; o.z = (_Float16)v.z; o.w = (_Float16)v.w;
        int r = i >> 6, c4g = i & 63;            // 64 4-col groups per row
        int shard = c4g >> 3, within = c4g & 7;  // 8 groups per 32-col shard
        ((half4*)h16)[((size_t)shard * MPAD + r) * 8 + within] = o;
    } else if (b < CONV_B + WPK_B) {
        // Pre-pack W (fp32 [256,256], k-major) into fp16 MFMA B-fragments for
        // mfma_f32_32x32x16_f16. Fragment (ks,nb): lane l holds
        // B[ks*16 + (l>>5)*8 + j][nb*32 + (l&31)], j=0..7.
        int tid  = (b - CONV_B) * 256 + threadIdx.x;  // 6*16*8*64 = 49152
        int lane = tid & 63;
        int nb   = (tid >> 6) & 7;
        int ks   = (tid >> 9) & 15;
        int w    = tid >> 13;
        if (w >= 6) return;
        int l = w >> 1, s = w & 1;
        const float* W = (s == 0 ? Ws1 : Ws2) + (size_t)l * DD * DD;
        int kbase = ks * 16 + (lane >> 5) * 8;
        int n     = nb * 32 + (lane & 31);
        half8 hi;
#pragma unroll
        for (int j = 0; j < 8; ++j) hi[j] = (_Float16)W[(size_t)(kbase + j) * DD + n];
        ((half8*)Wp)[(((size_t)w * 16 + ks) * 8 + nb) * 64 + lane] = hi;
    } else {
        int i = (b - CONV_B - WPK_B) * 256 + threadIdx.x;
        if (i < EE) atomicAdd(&deg[dst[i]], 1);
    }
}

// ---------------------------------------------------------------------------
// CSR build: 3-kernel parallel scan -> scatter (histogram is in k_prep)
// ---------------------------------------------------------------------------
__global__ void k_scan1(const int* __restrict__ deg, int* __restrict__ rp,
                        int* __restrict__ bsum, int n) {
    __shared__ int s[1024];
    int t = threadIdx.x;
    int i = blockIdx.x * 1024 + t;
    int v = (i < n) ? deg[i] : 0;
    s[t] = v;
    __syncthreads();
    for (int off = 1; off < 1024; off <<= 1) {
        int tmp = (t >= off) ? s[t - off] : 0;
        __syncthreads();
        s[t] += tmp;
        __syncthreads();
    }
    if (i < n) rp[i] = s[t] - v;          // local exclusive
    if (t == 1023) bsum[blockIdx.x] = s[1023];
}

__global__ void k_scan2(int* __restrict__ bsum, int nb, int* __restrict__ total_out) {
    int lane = threadIdx.x & 63;
    int v = (lane < nb) ? bsum[lane] : 0;
    int orig = v;
    for (int off = 1; off < 64; off <<= 1) {
        int u = __shfl_up(v, off);
        if (lane >= off) v += u;
    }
    if (lane < nb) bsum[lane] = v - orig;  // exclusive block offsets
    if (lane == 63) *total_out = v;        // grand total -> row_ptr[N]
}

__global__ void k_scan3(int* __restrict__ rp, const int* __restrict__ bsum,
                        int* __restrict__ cursor, int n) {
    int i = blockIdx.x * 1024 + threadIdx.x;
    if (i < n) {
        int v = rp[i] + bsum[blockIdx.x];
        rp[i] = v;
        cursor[i] = v;
    }
}

__global__ void k_scatter(const int* __restrict__ src, const int* __restrict__ dst,
                          int* __restrict__ cursor, int* __restrict__ csr_src, int e) {
    int i = blockIdx.x * blockDim.x + threadIdx.x;
    if (i < e) {
        int d = dst[i];
        int pos = atomicAdd(&cursor[d], 1);
        csr_src[pos] = src[i];
    }
}

// ---------------------------------------------------------------------------
// XCD-sharded, lane-sequential aggregation: agg[n] = h[n] + sum_{j->n} h[j].
// Shard = blockIdx & 7 -> consecutive blocks round-robin across XCDs; shard
// k's 3.2 MB h slice stays L2-resident on XCD k (round 5: FETCH 185->26 MB).
// Structure (round 6, never isolated until now):
//   - 4 lanes per node x 16 nodes per wave; each lane owns one 16 B part of
//     its node's 64 B shard row and accumulates SEQUENTIALLY -> no
//     cross-lane reduction at all;
//   - 8-deep two-pass batches: 8 idx loads (1 wait), 8 row loads (1 wait),
//     8 pk-adds -> ~0.13 VMEM instr per edge-visit;
//   - 6256 blocks, no LDS, low VGPR -> max occupancy for latency hiding.
// csr_src nontemporal (no L2 allocate, protects h residency).
// agg written ROW-major via nt stores (mlp streams it from HBM at BW;
// keeping it out of L2 avoids evicting the h shard).
// ---------------------------------------------------------------------------
__global__ __launch_bounds__(256) void k_gather(
        const _Float16* __restrict__ h,
        const int* __restrict__ row_ptr,
        const int* __restrict__ csr_src,
        _Float16* __restrict__ agg) {
    int t = threadIdx.x, lane = t & 63, w = t >> 6;
    int shard = blockIdx.x & 7;
    int grp   = blockIdx.x >> 3;           // 782 groups of 64 nodes
    int nsub  = lane >> 2;                 // 16 nodes per wave
    int part  = lane & 3;                  // 16 B part within 64 B shard row
    int n = grp * 64 + w * 16 + nsub;
    const half8* hp8 = (const half8*)h;
    size_t sbase = (size_t)shard * MPAD;

    int beg = 0, end = 0;
    if (n < NN) { beg = row_ptr[n]; end = row_ptr[n + 1]; }

    half8 acc;
#pragma unroll
    for (int i = 0; i < 8; ++i) acc[i] = (_Float16)0;
    if (n < NN) acc = hp8[(sbase + n) * 4 + part];   // self row

    int j = beg;
    while (__any(j < end)) {
        // pass 1: 8 independent index loads (4 lanes/node coalesce)
        int idx[8];
#pragma unroll
        for (int u = 0; u < 8; ++u) {
            int e = j + u;
            idx[u] = (e < end) ? __builtin_nontemporal_load(&csr_src[e]) : -1;
        }
        // pass 2: 8 independent row loads (predicated), then accumulate
        half8 v[8];
#pragma unroll
        for (int u = 0; u < 8; ++u) {
#pragma unroll
            for (int i = 0; i < 8; ++i) v[u][i] = (_Float16)0;
            if (idx[u] >= 0) v[u] = hp8[(sbase + idx[u]) * 4 + part];
        }
#pragma unroll
        for (int u = 0; u < 8; ++u) acc += v[u];
        j += 8;
    }

    if (n < NN)
        __builtin_nontemporal_store(
            *(int4v*)&acc,
            (int4v*)agg + (size_t)n * 32 + shard * 4 + part);  // row-major
}

// ---------------------------------------------------------------------------
// Fused MLP + pool-accumulate (round-7 proven 32-row tile):
// h_out = relu(relu(A@W1+b1)@W2+b2). Block: 4 waves over 32x256; wave w owns
// 32x64 (2 n-tiles of mfma_f32_32x32x16_f16). Grid 1564 -> 24.4 waves/CU.
// A row-major, regular loads (streams from HBM/L3 at BW).
// Hout written SHARD-MAJOR (next gather's layout), nt; skipped last layer.
// Fout nontemporal; per-graph pool partials atomically into Gout.
// ---------------------------------------------------------------------------
__global__ __launch_bounds__(256) void k_mlp(
        const _Float16* __restrict__ A,    // agg16 [MPAD, 256] row-major
        const int* __restrict__ batch,
        const _Float16* __restrict__ Wp1, const float* __restrict__ b1,
        const _Float16* __restrict__ Wp2, const float* __restrict__ b2,
        _Float16* __restrict__ Hout,       // h16 shard-major (or nullptr)
        float* __restrict__ Fout,          // node_embed + l*256, row stride 768
        float* __restrict__ Gout) {        // gsum + l*256, row stride 768
    __shared__ _Float16 t_lds[32 * 256];   // 16 KB
    __shared__ int batch_s[32];
    int t    = threadIdx.x;
    int lane = t & 63;
    int w    = t >> 6;                     // wave = n-quadrant [w*64, w*64+64)
    int r0   = blockIdx.x * 32;

    if (t < 32) {
        int r = r0 + t;
        batch_s[t] = (r < NN) ? batch[r] : 0x7fffffff;
    }

    // ---- GEMM1: acc = A @ W1 (A fragments direct from global) ----
    int arow = r0 + (lane & 31);
    const half8* baseA = (const half8*)(A + (size_t)arow * DD) + (lane >> 5);
    const half8* B1    = (const half8*)Wp1;

    floatx16 acc[2];
#pragma unroll
    for (int nt = 0; nt < 2; ++nt)
#pragma unroll
        for (int i = 0; i < 16; ++i) acc[nt][i] = 0.0f;

#pragma unroll 4
    for (int ks = 0; ks < 16; ++ks) {
        half8 a = baseA[ks * 2];
#pragma unroll
        for (int nt = 0; nt < 2; ++nt) {
            half8 b = B1[(size_t)(ks * 8 + w * 2 + nt) * 64 + lane];
            acc[nt] = __builtin_amdgcn_mfma_f32_32x32x16_f16(a, b, acc[nt], 0, 0, 0);
        }
    }

    // ---- epilogue 1: t = relu(acc + b1) -> LDS (fp16, swizzled) ----
#pragma unroll
    for (int nt = 0; nt < 2; ++nt) {
        int c  = w * 64 + nt * 32 + (lane & 31);
        float bv = b1[c];
#pragma unroll
        for (int reg = 0; reg < 16; ++reg) {
            int lr = (reg & 3) + 8 * (reg >> 2) + 4 * (lane >> 5);  // 0..31
            float v = fmaxf(acc[nt][reg] + bv, 0.0f);
            t_lds[lr * 256 + ((((c >> 3) ^ (lr & 7)) << 3) | (c & 7))] = (_Float16)v;
        }
    }
    __syncthreads();

    // ---- GEMM2: acc2 = t @ W2 (A fragments from swizzled LDS) ----
    const half8* B2 = (const half8*)Wp2;
    int r = lane & 31;
    floatx16 acc2[2];
#pragma unroll
    for (int nt = 0; nt < 2; ++nt)
#pragma unroll
        for (int i = 0; i < 16; ++i) acc2[nt][i] = 0.0f;

#pragma unroll 4
    for (int ks = 0; ks < 16; ++ks) {
        int kblk = ks * 2 + (lane >> 5);
        half8 a = *(const half8*)&t_lds[r * 256 + ((kblk ^ (r & 7)) << 3)];
#pragma unroll
        for (int nt = 0; nt < 2; ++nt) {
            half8 b = B2[(size_t)(ks * 8 + w * 2 + nt) * 64 + lane];
            acc2[nt] = __builtin_amdgcn_mfma_f32_32x32x16_f16(a, b, acc2[nt], 0, 0, 0);
        }
    }

    // ---- epilogue 2: h = relu(acc2 + b2) -> shard-major Hout + Fout ----
    const int rbase = 4 * (lane >> 5);
#pragma unroll
    for (int nt = 0; nt < 2; ++nt) {
        int col   = w * 64 + nt * 32 + (lane & 31);
        int shard = w * 2 + nt;            // col >> 5
        float bv = b2[col];
#pragma unroll
        for (int reg = 0; reg < 16; ++reg) {
            int rowid = rbase + (reg & 3) + 8 * (reg >> 2);   // 0..31
            int row = r0 + rowid;
            if (row < NN) {
                float v = fmaxf(acc2[nt][reg] + bv, 0.0f);
                if (Hout)
                    __builtin_nontemporal_store(
                        (_Float16)v,
                        &Hout[((size_t)shard * MPAD + row) * 32 + (lane & 31)]);
                __builtin_nontemporal_store(v, &Fout[(size_t)row * 768 + col]);
            }
        }
    }

    // ---- pool accumulate: per-graph column sums (batch sorted; the tile's
    //      32 rows span 1-2 graphs). Cross-half merge by shfl_xor(32),
    //      then one atomicAdd per (graph, col) partial.
    int lastid = NN - 1 - r0;
    if (lastid >= 0) {
        if (lastid > 31) lastid = 31;
        int g0 = batch_s[0];
        int g1 = batch_s[lastid];
        for (int g = g0; g <= g1; ++g) {
#pragma unroll
            for (int nt = 0; nt < 2; ++nt) {
                int col = w * 64 + nt * 32 + (lane & 31);
                float bv = b2[col];
                float s = 0.0f;
#pragma unroll
                for (int reg = 0; reg < 16; ++reg) {
                    int rowid = rbase + (reg & 3) + 8 * (reg >> 2);
                    if (batch_s[rowid] == g)
                        s += fmaxf(acc2[nt][reg] + bv, 0.0f);
                }
                s += __shfl_xor(s, 32);
                if (lane < 32)
                    atomicAdd(&Gout[(size_t)g * 768 + col], s);
            }
        }
    }
}

// ---------------------------------------------------------------------------
// Finalize pool: graph_embed = gsum / count. One block per graph.
// ---------------------------------------------------------------------------
__global__ void k_pool_final(const float* __restrict__ gsum,
                             const int* __restrict__ batch,
                             float* __restrict__ graph_embed) {
    int g = blockIdx.x;
    int t = threadIdx.x;  // 0..191
    int start, end;
    { int l = 0, h = NN; while (l < h) { int m = (l + h) >> 1; if (batch[m] < g) l = m + 1; else h = m; } start = l; }
    { int l = 0, h = NN; while (l < h) { int m = (l + h) >> 1; if (batch[m] < g + 1) l = m + 1; else h = m; } end = l; }
    int cnt = end - start;
    float inv = 1.0f / (float)(cnt > 0 ? cnt : 1);
    float4 v = ((const float4*)(gsum + (size_t)g * 768))[t];
    float4 o; o.x = v.x * inv; o.y = v.y * inv; o.z = v.z * inv; o.w = v.w * inv;
    ((float4*)(graph_embed + (size_t)g * 768))[t] = o;
}

// ---------------------------------------------------------------------------
extern "C" void kernel_launch(void* const* d_in, const int* in_sizes, int n_in,
                              void* d_out, int out_size, void* d_ws, size_t ws_size,
                              hipStream_t stream) {
    const float* x     = (const float*)d_in[0];  // [N, 256]
    const int*   ei    = (const int*)d_in[1];    // [2, E]
    const int*   batch = (const int*)d_in[2];    // [N] (sorted)
    const float* Ws1   = (const float*)d_in[3];  // [L, 256, 256]
    const float* bs1   = (const float*)d_in[4];  // [L, 256]
    const float* Ws2   = (const float*)d_in[5];  // [L, 256, 256]
    const float* bs2   = (const float*)d_in[6];  // [L, 256]

    float* out         = (float*)d_out;
    float* graph_embed = out;                     // [G, 768]
    float* node_embed  = out + (size_t)GG * 768;  // [N, 768]

    // Workspace (re-poisoned before every call; fully rebuilt here).
    // Single h buffer (gather and mlp are serialized kernel launches:
    // gather(l) fully reads h before mlp(l) overwrites it).
    _Float16* h16   = (_Float16*)d_ws;                  // [8][MPAD][32] shard-major
    _Float16* agg16 = h16 + (size_t)MPAD * DD;          // [MPAD, 256] row-major
    _Float16* Wp    = agg16 + (size_t)MPAD * DD;        // 6 * 65536 halfs
    float* gsum     = (float*)(Wp + (size_t)6 * 65536); // [G, 768]   (zeroed)
    int* cursor     = (int*)(gsum + (size_t)GG * 768);  // [N] (also deg, zeroed)
    int* bsum       = cursor + NN;                      // [64]       (zeroed)
    int* csr_src    = bsum + 64;                        // [E]
    int* row_ptr    = csr_src + EE;                     // [N+1]

    const int* src = ei;       // edge_index[0]
    const int* dst = ei + EE;  // edge_index[1]

    const int NB = (NN + 1023) / 1024;  // 49 scan blocks

    // Zero gsum + cursor + bsum in one contiguous memset (before k_prep hist!)
    hipMemsetAsync(gsum, 0, (size_t)GG * 768 * 4 + (size_t)NN * 4 + 64 * 4, stream);

    // convert + wpack + hist in one launch
    k_prep<<<CONV_B + WPK_B + HIST_B, 256, 0, stream>>>(x, h16, Ws1, Ws2, Wp, dst, cursor);

    // Finish CSR (dst -> list of src)
    k_scan1<<<NB, 1024, 0, stream>>>(cursor, row_ptr, bsum, NN);
    k_scan2<<<1, 64, 0, stream>>>(bsum, NB, row_ptr + NN);
    k_scan3<<<NB, 1024, 0, stream>>>(row_ptr, bsum, cursor, NN);
    k_scatter<<<(EE + 255) / 256, 256, 0, stream>>>(src, dst, cursor, csr_src, EE);

    for (int l = 0; l < LL; ++l) {
        // agg = h + segment_sum(h[src], dst)   (XCD-sharded, lane-sequential)
        k_gather<<<GATHER_GRID, 256, 0, stream>>>(h16, row_ptr, csr_src, agg16);
        // h = relu(relu(agg@W1+b1)@W2+b2) -> h16 + node_embed + gsum partials
        k_mlp<<<MPAD / 32, 256, 0, stream>>>(
            agg16, batch,
            Wp + (size_t)(2 * l + 0) * 65536, bs1 + (size_t)l * DD,
            Wp + (size_t)(2 * l + 1) * 65536, bs2 + (size_t)l * DD,
            (l == LL - 1) ? nullptr : h16,
            node_embed + (size_t)l * DD, gsum + (size_t)l * DD);
    }

    k_pool_final<<<GG, 192, 0, stream>>>(gsum, batch, graph_embed);
}

// Round 10
// 529.561 us; speedup vs baseline: 1.3470x; 1.3470x over previous
//
#include <hip/hip_runtime.h>

// Problem constants (match reference setup_inputs)
#define NN 50000
#define EE 800000
#define DD 256
#define LL 3
#define GG 512
#define MPAD 50048   // row padding
#define FB   1563    // fused blocks: ceil(NN/32)

typedef __attribute__((ext_vector_type(4))) _Float16 half4;
typedef __attribute__((ext_vector_type(8))) _Float16 half8;
typedef __attribute__((ext_vector_type(16))) float floatx16;

// ---------------------------------------------------------------------------
// Fused prep kernel (independent work, split by blockIdx range):
//   [0, 12500)        : x fp32 -> fp16 convert (row-major h)
//   [12500, 12692)    : weight pack (192 blocks)
//   [12692, 15817)    : degree histogram (3125 blocks)
// ---------------------------------------------------------------------------
#define CONV_B 12500
#define WPK_B  192
#define HIST_B 3125

__global__ void k_prep(const float* __restrict__ x, _Float16* __restrict__ h16,
                       const float* __restrict__ Ws1, const float* __restrict__ Ws2,
                       _Float16* __restrict__ Wp,
                       const int* __restrict__ dst, int* __restrict__ deg) {
    int b = blockIdx.x;
    if (b < CONV_B) {
        int i = b * 256 + threadIdx.x;  // float4 groups, NN*DD/4 = 3.2M
        if (i >= NN * DD / 4) return;
        float4 v = ((const float4*)x)[i];
        half4 o;
        o.x = (_Float16)v.x; o.y = (_Float16)v.y; o.z = (_Float16)v.z; o.w = (_Float16)v.w;
        ((half4*)h16)[i] = o;
    } else if (b < CONV_B + WPK_B) {
        // Pre-pack W (fp32 [256,256], k-major) into fp16 MFMA B-fragments for
        // mfma_f32_32x32x16_f16. Fragment (ks,nb): lane l holds
        // B[ks*16 + (l>>5)*8 + j][nb*32 + (l&31)], j=0..7.
        int tid  = (b - CONV_B) * 256 + threadIdx.x;  // 6*16*8*64 = 49152
        int lane = tid & 63;
        int nb   = (tid >> 6) & 7;
        int ks   = (tid >> 9) & 15;
        int w    = tid >> 13;
        if (w >= 6) return;
        int l = w >> 1, s = w & 1;
        const float* W = (s == 0 ? Ws1 : Ws2) + (size_t)l * DD * DD;
        int kbase = ks * 16 + (lane >> 5) * 8;
        int n     = nb * 32 + (lane & 31);
        half8 hi;
#pragma unroll
        for (int j = 0; j < 8; ++j) hi[j] = (_Float16)W[(size_t)(kbase + j) * DD + n];
        ((half8*)Wp)[(((size_t)w * 16 + ks) * 8 + nb) * 64 + lane] = hi;
    } else {
        int i = (b - CONV_B - WPK_B) * 256 + threadIdx.x;
        if (i < EE) atomicAdd(&deg[dst[i]], 1);
    }
}

// ---------------------------------------------------------------------------
// CSR build: 3-kernel parallel scan -> scatter (histogram is in k_prep)
// ---------------------------------------------------------------------------
__global__ void k_scan1(const int* __restrict__ deg, int* __restrict__ rp,
                        int* __restrict__ bsum, int n) {
    __shared__ int s[1024];
    int t = threadIdx.x;
    int i = blockIdx.x * 1024 + t;
    int v = (i < n) ? deg[i] : 0;
    s[t] = v;
    __syncthreads();
    for (int off = 1; off < 1024; off <<= 1) {
        int tmp = (t >= off) ? s[t - off] : 0;
        __syncthreads();
        s[t] += tmp;
        __syncthreads();
    }
    if (i < n) rp[i] = s[t] - v;          // local exclusive
    if (t == 1023) bsum[blockIdx.x] = s[1023];
}

__global__ void k_scan2(int* __restrict__ bsum, int nb, int* __restrict__ total_out) {
    int lane = threadIdx.x & 63;
    int v = (lane < nb) ? bsum[lane] : 0;
    int orig = v;
    for (int off = 1; off < 64; off <<= 1) {
        int u = __shfl_up(v, off);
        if (lane >= off) v += u;
    }
    if (lane < nb) bsum[lane] = v - orig;  // exclusive block offsets
    if (lane == 63) *total_out = v;        // grand total -> row_ptr[N]
}

__global__ void k_scan3(int* __restrict__ rp, const int* __restrict__ bsum,
                        int* __restrict__ cursor, int n) {
    int i = blockIdx.x * 1024 + threadIdx.x;
    if (i < n) {
        int v = rp[i] + bsum[blockIdx.x];
        rp[i] = v;
        cursor[i] = v;
    }
}

__global__ void k_scatter(const int* __restrict__ src, const int* __restrict__ dst,
                          int* __restrict__ cursor, int* __restrict__ csr_src, int e) {
    int i = blockIdx.x * blockDim.x + threadIdx.x;
    if (i < e) {
        int d = dst[i];
        int pos = atomicAdd(&cursor[d], 1);
        csr_src[pos] = src[i];
    }
}

// ---------------------------------------------------------------------------
// Fused layer kernel: gather -> (LDS) -> MLP -> pool, one block per 32 rows.
//   Phase G: block stages its CSR span (expected 512 edges) in LDS; each of
//     the 4 waves gathers 8 rows (round-3 edge loop: lanes 0-31 even edges /
//     32-63 odd, 8 half8 loads in flight, shfl_xor(32) fold) and writes the
//     result STRAIGHT INTO the swizzled LDS A-tile. agg never exists in
//     global memory (saves 25.6 MB write + 25.6 MB read per layer).
//   GEMM1 reads A-fragments from LDS (zero global A traffic); t = relu(.)
//     overwrites the same 16 KB tile; GEMM2; epilogue writes h (regular,
//     row-major; next layer's gather wants it cached) + node_embed (nt) and
//     accumulates per-graph pool partials.
// 1563 blocks x 4 waves ~ 20-24 waves/CU: blocks in the latency-bound gather
// phase co-schedule with blocks in the MFMA phase (separate pipes).
// h double-buffered across layers (gather reads any h row; race otherwise).
// ---------------------------------------------------------------------------
__global__ __launch_bounds__(256) void k_layer(
        const _Float16* __restrict__ hin,  // [MPAD, 256] row-major
        const int* __restrict__ row_ptr,
        const int* __restrict__ csr_src,
        const int* __restrict__ batch,
        const _Float16* __restrict__ Wp1, const float* __restrict__ b1,
        const _Float16* __restrict__ Wp2, const float* __restrict__ b2,
        _Float16* __restrict__ Hout,       // [MPAD, 256] (nullptr on last layer)
        float* __restrict__ Fout,          // node_embed + l*256, row stride 768
        float* __restrict__ Gout) {        // gsum + l*256, row stride 768
    __shared__ _Float16 t_lds[32 * 256];   // 16 KB: A-tile, then t
    __shared__ int eidx[1536];             // 6 KB: block's CSR span
    __shared__ int rp_s[33];
    __shared__ int batch_s[32];
    int t    = threadIdx.x;
    int lane = t & 63;
    int w    = t >> 6;
    int r0   = blockIdx.x * 32;

    // ---- stage row_ptr span + edge indices + batch ids ----
    if (t < 33) {
        int nn = r0 + t;
        if (nn > NN) nn = NN;
        rp_s[t] = row_ptr[nn];
    }
    if (t >= 64 && t < 96) {
        int r = r0 + (t - 64);
        batch_s[t - 64] = (r < NN) ? batch[r] : 0x7fffffff;
    }
    __syncthreads();
    int beg0 = rp_s[0];
    int cnt  = rp_s[32] - beg0;
    for (int i = t; i < cnt && i < 1536; i += 256) eidx[i] = csr_src[beg0 + i];
    __syncthreads();

    // ---- Phase G: each wave gathers 8 rows into the swizzled A-tile ----
    int hf = lane >> 5;   // 0: own row + even edges; 1: odd edges
    int cl = lane & 31;   // column group: cols [cl*8, cl*8+8)
    const half8* hp = (const half8*)hin;
    for (int i = 0; i < 8; ++i) {
        int lr = w * 8 + i;
        int n  = r0 + lr;               // wave-uniform
        if (n >= NN) break;
        int beg = rp_s[lr] - beg0, end = rp_s[lr + 1] - beg0;

        half8 acc;
#pragma unroll
        for (int q = 0; q < 8; ++q) acc[q] = (_Float16)0;
        if (hf == 0) acc = hp[(size_t)n * 32 + cl];

        if (end <= 1536) {
            // fast path: indices from LDS
            int k = beg;
            for (; k + 16 <= end; k += 16) {
                half8 v[8];
#pragma unroll
                for (int u = 0; u < 8; ++u) {
                    int s = eidx[k + 2 * u + hf];
                    v[u] = hp[(size_t)s * 32 + cl];
                }
#pragma unroll
                for (int u = 0; u < 8; ++u) acc += v[u];
            }
            if (k < end) {  // tail < 16 edges: predicated, loads in flight
#pragma unroll
                for (int u = 0; u < 8; ++u) {
                    int e = k + 2 * u + hf;
                    half8 v;
#pragma unroll
                    for (int q = 0; q < 8; ++q) v[q] = (_Float16)0;
                    if (e < end) v = hp[(size_t)eidx[e] * 32 + cl];
                    acc += v;
                }
            }
        } else {
            // rare fallback: indices from global
            int k = beg;
            for (; k + 16 <= end; k += 16) {
                half8 v[8];
#pragma unroll
                for (int u = 0; u < 8; ++u) {
                    int s = csr_src[beg0 + k + 2 * u + hf];
                    v[u] = hp[(size_t)s * 32 + cl];
                }
#pragma unroll
                for (int u = 0; u < 8; ++u) acc += v[u];
            }
            if (k < end) {
#pragma unroll
                for (int u = 0; u < 8; ++u) {
                    int e = k + 2 * u + hf;
                    half8 v;
#pragma unroll
                    for (int q = 0; q < 8; ++q) v[q] = (_Float16)0;
                    if (e < end) v = hp[(size_t)csr_src[beg0 + e] * 32 + cl];
                    acc += v;
                }
            }
        }

        // fold odd-half into even-half, write swizzled LDS A-tile
        int4 ai = *(int4*)&acc;
        int4 bi;
        bi.x = __shfl_xor(ai.x, 32);
        bi.y = __shfl_xor(ai.y, 32);
        bi.z = __shfl_xor(ai.z, 32);
        bi.w = __shfl_xor(ai.w, 32);
        acc += *(half8*)&bi;
        if (hf == 0)
            *(half8*)&t_lds[lr * 256 + ((cl ^ (lr & 7)) << 3)] = acc;
    }
    __syncthreads();

    // ---- GEMM1: acc = A @ W1 (A fragments from swizzled LDS) ----
    const half8* B1 = (const half8*)Wp1;
    int rr = lane & 31;

    floatx16 acc1[2];
#pragma unroll
    for (int nt = 0; nt < 2; ++nt)
#pragma unroll
        for (int i = 0; i < 16; ++i) acc1[nt][i] = 0.0f;

#pragma unroll 4
    for (int ks = 0; ks < 16; ++ks) {
        int kblk = ks * 2 + (lane >> 5);
        half8 a = *(const half8*)&t_lds[rr * 256 + ((kblk ^ (rr & 7)) << 3)];
#pragma unroll
        for (int nt = 0; nt < 2; ++nt) {
            half8 b = B1[(size_t)(ks * 8 + w * 2 + nt) * 64 + lane];
            acc1[nt] = __builtin_amdgcn_mfma_f32_32x32x16_f16(a, b, acc1[nt], 0, 0, 0);
        }
    }
    __syncthreads();  // all waves done reading A before overwrite

    // ---- epilogue 1: t = relu(acc1 + b1) -> same LDS tile (swizzled) ----
#pragma unroll
    for (int nt = 0; nt < 2; ++nt) {
        int c  = w * 64 + nt * 32 + (lane & 31);
        float bv = b1[c];
#pragma unroll
        for (int reg = 0; reg < 16; ++reg) {
            int lr = (reg & 3) + 8 * (reg >> 2) + 4 * (lane >> 5);  // 0..31
            float v = fmaxf(acc1[nt][reg] + bv, 0.0f);
            t_lds[lr * 256 + ((((c >> 3) ^ (lr & 7)) << 3) | (c & 7))] = (_Float16)v;
        }
    }
    __syncthreads();

    // ---- GEMM2: acc2 = t @ W2 (A fragments from swizzled LDS) ----
    const half8* B2 = (const half8*)Wp2;
    floatx16 acc2[2];
#pragma unroll
    for (int nt = 0; nt < 2; ++nt)
#pragma unroll
        for (int i = 0; i < 16; ++i) acc2[nt][i] = 0.0f;

#pragma unroll 4
    for (int ks = 0; ks < 16; ++ks) {
        int kblk = ks * 2 + (lane >> 5);
        half8 a = *(const half8*)&t_lds[rr * 256 + ((kblk ^ (rr & 7)) << 3)];
#pragma unroll
        for (int nt = 0; nt < 2; ++nt) {
            half8 b = B2[(size_t)(ks * 8 + w * 2 + nt) * 64 + lane];
            acc2[nt] = __builtin_amdgcn_mfma_f32_32x32x16_f16(a, b, acc2[nt], 0, 0, 0);
        }
    }

    // ---- epilogue 2: h = relu(acc2 + b2) -> Hout (row-major) + Fout ----
    const int rbase = 4 * (lane >> 5);
#pragma unroll
    for (int nt = 0; nt < 2; ++nt) {
        int col = w * 64 + nt * 32 + (lane & 31);
        float bv = b2[col];
#pragma unroll
        for (int reg = 0; reg < 16; ++reg) {
            int rowid = rbase + (reg & 3) + 8 * (reg >> 2);   // 0..31
            int row = r0 + rowid;
            if (row < NN) {
                float v = fmaxf(acc2[nt][reg] + bv, 0.0f);
                if (Hout) Hout[(size_t)row * DD + col] = (_Float16)v;
                __builtin_nontemporal_store(v, &Fout[(size_t)row * 768 + col]);
            }
        }
    }

    // ---- pool accumulate: per-graph column sums (batch sorted; the tile's
    //      32 rows span 1-2 graphs). Cross-half merge by shfl_xor(32),
    //      then one atomicAdd per (graph, col) partial.
    int lastid = NN - 1 - r0;
    if (lastid >= 0) {
        if (lastid > 31) lastid = 31;
        int g0 = batch_s[0];
        int g1 = batch_s[lastid];
        for (int g = g0; g <= g1; ++g) {
#pragma unroll
            for (int nt = 0; nt < 2; ++nt) {
                int col = w * 64 + nt * 32 + (lane & 31);
                float bv = b2[col];
                float s = 0.0f;
#pragma unroll
                for (int reg = 0; reg < 16; ++reg) {
                    int rowid = rbase + (reg & 3) + 8 * (reg >> 2);
                    if (batch_s[rowid] == g)
                        s += fmaxf(acc2[nt][reg] + bv, 0.0f);
                }
                s += __shfl_xor(s, 32);
                if (lane < 32)
                    atomicAdd(&Gout[(size_t)g * 768 + col], s);
            }
        }
    }
}

// ---------------------------------------------------------------------------
// Finalize pool: graph_embed = gsum / count. One block per graph.
// ---------------------------------------------------------------------------
__global__ void k_pool_final(const float* __restrict__ gsum,
                             const int* __restrict__ batch,
                             float* __restrict__ graph_embed) {
    int g = blockIdx.x;
    int t = threadIdx.x;  // 0..191
    int start, end;
    { int l = 0, h = NN; while (l < h) { int m = (l + h) >> 1; if (batch[m] < g) l = m + 1; else h = m; } start = l; }
    { int l = 0, h = NN; while (l < h) { int m = (l + h) >> 1; if (batch[m] < g + 1) l = m + 1; else h = m; } end = l; }
    int cnt = end - start;
    float inv = 1.0f / (float)(cnt > 0 ? cnt : 1);
    float4 v = ((const float4*)(gsum + (size_t)g * 768))[t];
    float4 o; o.x = v.x * inv; o.y = v.y * inv; o.z = v.z * inv; o.w = v.w * inv;
    ((float4*)(graph_embed + (size_t)g * 768))[t] = o;
}

// ---------------------------------------------------------------------------
extern "C" void kernel_launch(void* const* d_in, const int* in_sizes, int n_in,
                              void* d_out, int out_size, void* d_ws, size_t ws_size,
                              hipStream_t stream) {
    const float* x     = (const float*)d_in[0];  // [N, 256]
    const int*   ei    = (const int*)d_in[1];    // [2, E]
    const int*   batch = (const int*)d_in[2];    // [N] (sorted)
    const float* Ws1   = (const float*)d_in[3];  // [L, 256, 256]
    const float* bs1   = (const float*)d_in[4];  // [L, 256]
    const float* Ws2   = (const float*)d_in[5];  // [L, 256, 256]
    const float* bs2   = (const float*)d_in[6];  // [L, 256]

    float* out         = (float*)d_out;
    float* graph_embed = out;                     // [G, 768]
    float* node_embed  = out + (size_t)GG * 768;  // [N, 768]

    // Workspace (re-poisoned before every call; fully rebuilt here).
    // h double-buffered: fused layer reads h(l-1) (arbitrary rows) while
    // writing h(l) (own rows) -- same buffer would race.
    _Float16* h16   = (_Float16*)d_ws;                  // [MPAD, 256]
    _Float16* h_alt = h16 + (size_t)MPAD * DD;          // [MPAD, 256]
    _Float16* Wp    = h_alt + (size_t)MPAD * DD;        // 6 * 65536 halfs
    float* gsum     = (float*)(Wp + (size_t)6 * 65536); // [G, 768]   (zeroed)
    int* cursor     = (int*)(gsum + (size_t)GG * 768);  // [N] (also deg, zeroed)
    int* bsum       = cursor + NN;                      // [64]       (zeroed)
    int* csr_src    = bsum + 64;                        // [E]
    int* row_ptr    = csr_src + EE;                     // [N+1]

    const int* src = ei;       // edge_index[0]
    const int* dst = ei + EE;  // edge_index[1]

    const int NB = (NN + 1023) / 1024;  // 49 scan blocks

    // Zero gsum + cursor + bsum in one contiguous memset (before k_prep hist!)
    hipMemsetAsync(gsum, 0, (size_t)GG * 768 * 4 + (size_t)NN * 4 + 64 * 4, stream);

    // convert + wpack + hist in one launch
    k_prep<<<CONV_B + WPK_B + HIST_B, 256, 0, stream>>>(x, h16, Ws1, Ws2, Wp, dst, cursor);

    // Finish CSR (dst -> list of src)
    k_scan1<<<NB, 1024, 0, stream>>>(cursor, row_ptr, bsum, NN);
    k_scan2<<<1, 64, 0, stream>>>(bsum, NB, row_ptr + NN);
    k_scan3<<<NB, 1024, 0, stream>>>(row_ptr, bsum, cursor, NN);
    k_scatter<<<(EE + 255) / 256, 256, 0, stream>>>(src, dst, cursor, csr_src, EE);

    for (int l = 0; l < LL; ++l) {
        const _Float16* hin  = (l & 1) ? h_alt : h16;
        _Float16*       hout = (l == LL - 1) ? nullptr : ((l & 1) ? h16 : h_alt);
        // fused gather (into LDS) + MLP + pool partials, one kernel per layer
        k_layer<<<FB, 256, 0, stream>>>(
            hin, row_ptr, csr_src, batch,
            Wp + (size_t)(2 * l + 0) * 65536, bs1 + (size_t)l * DD,
            Wp + (size_t)(2 * l + 1) * 65536, bs2 + (size_t)l * DD,
            hout, node_embed + (size_t)l * DD, gsum + (size_t)l * DD);
    }

    k_pool_final<<<GG, 192, 0, stream>>>(gsum, batch, graph_embed);
}